// Round 2
// baseline (1084.989 us; speedup 1.0000x reference)
//
#include <hip/hip_runtime.h>

#define NW 30000
#define ND 8192
#define DIM 300
#define DIM2 150
#define NNZA 600000
#define NNZX 524288
#define BN_SCALE 0.99999500003749971f

static inline int cdiv(int a, int b){ return (a + b - 1) / b; }

// ---------------- CSR build ----------------
__global__ void k_hist(const int* __restrict__ rows, int n, int* __restrict__ cnt){
  int i = blockIdx.x * blockDim.x + threadIdx.x;
  if (i < n) atomicAdd(&cnt[rows[i]], 1);
}

__global__ void k_copy_int(const int* __restrict__ a, int* __restrict__ b, int n){
  int i = blockIdx.x * blockDim.x + threadIdx.x;
  if (i < n) b[i] = a[i];
}

__global__ __launch_bounds__(1024) void k_scan(const int* __restrict__ cnt, int n, int* __restrict__ rp){
  __shared__ int sd[1024];
  __shared__ int carry;
  const int t = threadIdx.x;
  if (t == 0) carry = 0;
  __syncthreads();
  int nch = (n + 1023) >> 10;
  for (int c = 0; c < nch; ++c){
    int i = (c << 10) + t;
    int v = (i < n) ? cnt[i] : 0;
    sd[t] = v;
    __syncthreads();
    for (int o = 1; o < 1024; o <<= 1){
      int x = (t >= o) ? sd[t - o] : 0;
      __syncthreads();
      sd[t] += x;
      __syncthreads();
    }
    if (i < n) rp[i] = carry + sd[t] - v;
    __syncthreads();
    if (t == 1023) carry += sd[1023];
    __syncthreads();
  }
  if (t == 0) rp[n] = carry;
}

__global__ void k_scatter(const int* __restrict__ rows, const int* __restrict__ cols,
                          const float* __restrict__ vals, int n, int* __restrict__ cursor,
                          int* __restrict__ cs, float* __restrict__ vs){
  int i = blockIdx.x * blockDim.x + threadIdx.x;
  if (i < n){
    int r = rows[i];
    int p = atomicAdd(&cursor[r], 1);
    cs[p] = cols[i];
    vs[p] = vals[i];
  }
}

// ---------------- SpMM: one wave per output row, unroll-2, dual accumulators ----------------
__global__ __launch_bounds__(256) void k_spmm(const int* __restrict__ rp, const int* __restrict__ cs,
        const float* __restrict__ vs, const float* __restrict__ Hin, float* __restrict__ Hout, int nrows){
  int wid = (blockIdx.x * blockDim.x + threadIdx.x) >> 6;
  int lane = threadIdx.x & 63;
  if (wid >= nrows) return;
  int s = rp[wid], e = rp[wid + 1];
  float a0=0.f,a1=0.f,a2=0.f,a3=0.f,a4=0.f;
  float b0=0.f,b1=0.f,b2=0.f,b3=0.f,b4=0.f;
  const int d4 = 256 + lane;
  const bool t5 = d4 < DIM;
  int k = s;
  for (; k + 2 <= e; k += 2){
    int c0 = cs[k], c1 = cs[k+1];
    float v0 = vs[k], v1 = vs[k+1];
    const float* h0 = Hin + (size_t)c0 * DIM;
    const float* h1 = Hin + (size_t)c1 * DIM;
    float x0=h0[lane], x1=h0[lane+64], x2=h0[lane+128], x3=h0[lane+192];
    float y0=h1[lane], y1=h1[lane+64], y2=h1[lane+128], y3=h1[lane+192];
    float x4=0.f, y4=0.f;
    if (t5){ x4 = h0[d4]; y4 = h1[d4]; }
    a0=fmaf(v0,x0,a0); a1=fmaf(v0,x1,a1); a2=fmaf(v0,x2,a2); a3=fmaf(v0,x3,a3); a4=fmaf(v0,x4,a4);
    b0=fmaf(v1,y0,b0); b1=fmaf(v1,y1,b1); b2=fmaf(v1,y2,b2); b3=fmaf(v1,y3,b3); b4=fmaf(v1,y4,b4);
  }
  if (k < e){
    int c0 = cs[k];
    float v0 = vs[k];
    const float* h0 = Hin + (size_t)c0 * DIM;
    a0=fmaf(v0,h0[lane],a0); a1=fmaf(v0,h0[lane+64],a1); a2=fmaf(v0,h0[lane+128],a2); a3=fmaf(v0,h0[lane+192],a3);
    if (t5) a4=fmaf(v0,h0[d4],a4);
  }
  a0+=b0; a1+=b1; a2+=b2; a3+=b3; a4+=b4;
  float* o = Hout + (size_t)wid * DIM;
  o[lane]=a0; o[lane+64]=a1; o[lane+128]=a2; o[lane+192]=a3;
  if (t5) o[d4]=a4;
}

// ---------------- GEMM: C[M,N] = act(A[M,K] @ W[N,K]^T) ----------------
// 128x64 tile, 256 threads, 8x4 per thread, BK=32, transposed LDS staging.
__global__ __launch_bounds__(256) void k_gemm(const float* __restrict__ A, const float* __restrict__ W,
        const float* __restrict__ bias, const float* __restrict__ bng, const float* __restrict__ bnb,
        float* __restrict__ C, int M, int N, int K, int relu){
  __shared__ float As[32][132];   // stride 132: 16B-aligned rows, bank-clean f4 reads
  __shared__ float Bs[32][68];
  const int t  = threadIdx.x;
  const int tx = t & 15;          // N: 4 cols each
  const int ty = t >> 4;          // M: 8 rows each
  const int m0 = blockIdx.y << 7;
  const int n0 = blockIdx.x << 6;
  float acc[8][4] = {};
  for (int k0 = 0; k0 < K; k0 += 32){
    // stage A: 128 rows x 8 quads = 1024 quads, 4 per thread
    #pragma unroll
    for (int i = 0; i < 4; ++i){
      int q = t + (i << 8);
      int row = q >> 3, kq = q & 7;
      int gm = m0 + row, gk = k0 + (kq << 2);
      float4 av;
      if (gm < M && gk + 3 < K){
        av = *(const float4*)(A + (size_t)gm * K + gk);
      } else {
        av.x = (gm<M && gk  <K)? A[(size_t)gm*K+gk  ]:0.f;
        av.y = (gm<M && gk+1<K)? A[(size_t)gm*K+gk+1]:0.f;
        av.z = (gm<M && gk+2<K)? A[(size_t)gm*K+gk+2]:0.f;
        av.w = (gm<M && gk+3<K)? A[(size_t)gm*K+gk+3]:0.f;
      }
      int kk = kq << 2;
      As[kk  ][row]=av.x; As[kk+1][row]=av.y; As[kk+2][row]=av.z; As[kk+3][row]=av.w;
    }
    // stage B: 64 rows x 8 quads = 512 quads, 2 per thread
    #pragma unroll
    for (int i = 0; i < 2; ++i){
      int q = t + (i << 8);
      int row = q >> 3, kq = q & 7;
      int gn = n0 + row, gk = k0 + (kq << 2);
      float4 bv;
      if (gn < N && gk + 3 < K){
        bv = *(const float4*)(W + (size_t)gn * K + gk);
      } else {
        bv.x = (gn<N && gk  <K)? W[(size_t)gn*K+gk  ]:0.f;
        bv.y = (gn<N && gk+1<K)? W[(size_t)gn*K+gk+1]:0.f;
        bv.z = (gn<N && gk+2<K)? W[(size_t)gn*K+gk+2]:0.f;
        bv.w = (gn<N && gk+3<K)? W[(size_t)gn*K+gk+3]:0.f;
      }
      int kk = kq << 2;
      Bs[kk  ][row]=bv.x; Bs[kk+1][row]=bv.y; Bs[kk+2][row]=bv.z; Bs[kk+3][row]=bv.w;
    }
    __syncthreads();
    #pragma unroll
    for (int kk = 0; kk < 32; ++kk){
      float4 va0 = *(const float4*)(&As[kk][ty << 3]);
      float4 va1 = *(const float4*)(&As[kk][(ty << 3) | 4]);
      float4 vb  = *(const float4*)(&Bs[kk][tx << 2]);
      float av_[8] = {va0.x,va0.y,va0.z,va0.w,va1.x,va1.y,va1.z,va1.w};
      float bv_[4] = {vb.x,vb.y,vb.z,vb.w};
      #pragma unroll
      for (int i = 0; i < 8; ++i)
        #pragma unroll
        for (int j = 0; j < 4; ++j)
          acc[i][j] = fmaf(av_[i], bv_[j], acc[i][j]);
    }
    __syncthreads();
  }
  #pragma unroll
  for (int i = 0; i < 8; ++i){
    int m = m0 + (ty << 3) + i;
    if (m >= M) continue;
    #pragma unroll
    for (int j = 0; j < 4; ++j){
      int n = n0 + (tx << 2) + j;
      if (n >= N) continue;
      float v = acc[i][j];
      if (bias) v += bias[n];
      if (bng)  v = v * (bng[n] * BN_SCALE) + bnb[n];
      if (relu) v = fmaxf(v, 0.f);
      C[(size_t)m * N + n] = v;
    }
  }
}

// ---------------- residual + LayerNorm, output S = LN(0.3*emb + 0.7*H) + emb ----------------
__global__ __launch_bounds__(64) void k_res_ln(const float* __restrict__ emb, const float* __restrict__ Hin,
        const float* __restrict__ g, const float* __restrict__ b, float* __restrict__ S){
  int row = blockIdx.x;
  int lane = threadIdx.x;
  const float* e = emb + (size_t)row * DIM;
  const float* h = Hin + (size_t)row * DIM;
  float x[5], ev[5];
  float sum = 0.f, sq = 0.f;
  #pragma unroll
  for (int j = 0; j < 5; ++j){
    int d = j * 64 + lane;
    float v = 0.f, ee = 0.f;
    if (d < DIM){ ee = e[d]; v = 0.3f * ee + 0.7f * h[d]; }
    ev[j] = ee; x[j] = v; sum += v; sq = fmaf(v, v, sq);
  }
  #pragma unroll
  for (int o = 32; o > 0; o >>= 1){ sum += __shfl_down(sum, o); sq += __shfl_down(sq, o); }
  sum = __shfl(sum, 0); sq = __shfl(sq, 0);
  const float inv = 1.f / (float)DIM;
  float mu = sum * inv;
  float var = sq * inv - mu * mu;
  float rs = rsqrtf(var + 1e-5f);
  float* o = S + (size_t)row * DIM;
  #pragma unroll
  for (int j = 0; j < 5; ++j){
    int d = j * 64 + lane;
    if (d < DIM) o[d] = (x[j] - mu) * rs * g[d] + b[d] + ev[j];
  }
}

// ---------------- tiny classifier: [ND,150] @ [2,150]^T + b ----------------
__global__ void k_clf(const float* __restrict__ h2, const float* __restrict__ w,
                      const float* __restrict__ bias, float* __restrict__ out){
  int m = blockIdx.x * blockDim.x + threadIdx.x;
  if (m >= ND) return;
  const float* hr = h2 + (size_t)m * DIM2;
  float s0 = bias[0], s1 = bias[1];
  for (int k = 0; k < DIM2; ++k){
    float hv = hr[k];
    s0 = fmaf(hv, w[k], s0);
    s1 = fmaf(hv, w[DIM2 + k], s1);
  }
  out[m * 2] = s0;
  out[m * 2 + 1] = s1;
}

extern "C" void kernel_launch(void* const* d_in, const int* in_sizes, int n_in,
                              void* d_out, int out_size, void* d_ws, size_t ws_size,
                              hipStream_t stream){
  const int*   a_rows = (const int*)  d_in[0];
  const int*   a_cols = (const int*)  d_in[1];
  const float* a_vals = (const float*)d_in[2];
  const int*   x_rows = (const int*)  d_in[3];
  const int*   x_cols = (const int*)  d_in[4];
  const float* x_vals = (const float*)d_in[5];
  const float* emb    = (const float*)d_in[6];
  const float* w1     = (const float*)d_in[7];
  const float* w2     = (const float*)d_in[8];
  const float* w3     = (const float*)d_in[9];
  const float* ln_g   = (const float*)d_in[10];
  const float* ln_b   = (const float*)d_in[11];
  const float* m_w1   = (const float*)d_in[12];
  const float* m_b1   = (const float*)d_in[13];
  const float* bn1_g  = (const float*)d_in[14];
  const float* bn1_b  = (const float*)d_in[15];
  const float* m_w2   = (const float*)d_in[16];
  const float* m_b2   = (const float*)d_in[17];
  const float* bn2_g  = (const float*)d_in[18];
  const float* bn2_b  = (const float*)d_in[19];
  const float* clf_w  = (const float*)d_in[20];
  const float* clf_b  = (const float*)d_in[21];
  float* out = (float*)d_out;

  char* ws = (char*)d_ws;
  size_t off = 0;
  auto take = [&](size_t nbytes)->void*{
    void* p = ws + off;
    off += (nbytes + 255) & ~(size_t)255;
    return p;
  };
  int*   a_rp   = (int*)  take((NW + 1) * sizeof(int));
  int*   a_cs   = (int*)  take((size_t)NNZA * 4);
  float* a_vs   = (float*)take((size_t)NNZA * 4);
  int*   x_rp   = (int*)  take((ND + 1) * sizeof(int));
  int*   x_cs   = (int*)  take((size_t)NNZX * 4);
  float* x_vs   = (float*)take((size_t)NNZX * 4);
  int*   cursor = (int*)  take((size_t)NW * 4);
  float* T      = (float*)take((size_t)NW * DIM * 4);
  float* H      = (float*)take((size_t)NW * DIM * 4);
  float* docH = H;                         // H3 is dead by the time these are written
  float* h1   = H + (size_t)ND * DIM;
  float* h2   = H + (size_t)2 * ND * DIM;

  // ---- build CSR for A ----
  hipMemsetAsync(cursor, 0, NW * 4, stream);
  k_hist<<<cdiv(NNZA, 256), 256, 0, stream>>>(a_rows, NNZA, cursor);
  k_scan<<<1, 1024, 0, stream>>>(cursor, NW, a_rp);
  k_copy_int<<<cdiv(NW, 256), 256, 0, stream>>>(a_rp, cursor, NW);
  k_scatter<<<cdiv(NNZA, 256), 256, 0, stream>>>(a_rows, a_cols, a_vals, NNZA, cursor, a_cs, a_vs);
  // ---- build CSR for X ----
  hipMemsetAsync(cursor, 0, ND * 4, stream);
  k_hist<<<cdiv(NNZX, 256), 256, 0, stream>>>(x_rows, NNZX, cursor);
  k_scan<<<1, 1024, 0, stream>>>(cursor, ND, x_rp);
  k_copy_int<<<cdiv(ND, 256), 256, 0, stream>>>(x_rp, cursor, ND);
  k_scatter<<<cdiv(NNZX, 256), 256, 0, stream>>>(x_rows, x_cols, x_vals, NNZX, cursor, x_cs, x_vs);

  dim3 gg(cdiv(DIM, 64), cdiv(NW, 128));
  // ---- word GCN ----
  k_spmm<<<cdiv(NW, 4), 256, 0, stream>>>(a_rp, a_cs, a_vs, emb, T, NW);
  k_gemm<<<gg, 256, 0, stream>>>(T, w1, nullptr, nullptr, nullptr, H, NW, DIM, DIM, 1);
  k_spmm<<<cdiv(NW, 4), 256, 0, stream>>>(a_rp, a_cs, a_vs, H, T, NW);
  k_gemm<<<gg, 256, 0, stream>>>(T, w2, nullptr, nullptr, nullptr, H, NW, DIM, DIM, 1);
  k_spmm<<<cdiv(NW, 4), 256, 0, stream>>>(a_rp, a_cs, a_vs, H, T, NW);
  k_gemm<<<gg, 256, 0, stream>>>(T, w3, nullptr, nullptr, nullptr, H, NW, DIM, DIM, 1);
  // ---- residual + LN; S = word_H + emb (fuses the two doc SpMMs into one) ----
  k_res_ln<<<NW, 64, 0, stream>>>(emb, H, ln_g, ln_b, T);
  // ---- doc aggregation ----
  k_spmm<<<cdiv(ND, 4), 256, 0, stream>>>(x_rp, x_cs, x_vs, T, docH, ND);
  // ---- MLP head ----
  dim3 g1(cdiv(DIM, 64), cdiv(ND, 128));
  k_gemm<<<g1, 256, 0, stream>>>(docH, m_w1, m_b1, bn1_g, bn1_b, h1, ND, DIM, DIM, 1);
  dim3 g2(cdiv(DIM2, 64), cdiv(ND, 128));
  k_gemm<<<g2, 256, 0, stream>>>(h1, m_w2, m_b2, bn2_g, bn2_b, h2, ND, DIM2, DIM, 1);
  k_clf<<<cdiv(ND, 256), 256, 0, stream>>>(h2, clf_w, clf_b, out);
}

// Round 3
// 601.987 us; speedup vs baseline: 1.8023x; 1.8023x over previous
//
#include <hip/hip_runtime.h>

#define NW 30000
#define ND 8192
#define DIM 300
#define DIM2 150
#define NNZA 600000
#define NNZX 524288
#define PD 320            // padded feature stride (bf16 elems)
#define PD_U 160          // padded stride in uint (2 bf16 each)
#define BN_SCALE 0.99999500003749971f

typedef unsigned int uint;
typedef unsigned short ushort;
typedef __attribute__((ext_vector_type(8))) short bf16x8;
typedef __attribute__((ext_vector_type(4))) float f32x4;

static inline int cdiv(int a, int b){ return (a + b - 1) / b; }

__device__ __forceinline__ float b2f_lo(uint u){ return __builtin_bit_cast(float, u << 16); }
__device__ __forceinline__ float b2f_hi(uint u){ return __builtin_bit_cast(float, u & 0xffff0000u); }
__device__ __forceinline__ ushort f2b(float f){
  uint u = __builtin_bit_cast(uint, f);
  u += 0x7fffu + ((u >> 16) & 1u);
  return (ushort)(u >> 16);
}
__device__ __forceinline__ uint packb(float x, float y){
  return (uint)f2b(x) | ((uint)f2b(y) << 16);
}

// ---------------- CSR build ----------------
__global__ void k_hist(const int* __restrict__ rows, int n, int* __restrict__ cnt){
  int i = blockIdx.x * blockDim.x + threadIdx.x;
  if (i < n) atomicAdd(&cnt[rows[i]], 1);
}

__global__ void k_copy_int(const int* __restrict__ a, int* __restrict__ b, int n){
  int i = blockIdx.x * blockDim.x + threadIdx.x;
  if (i < n) b[i] = a[i];
}

__global__ __launch_bounds__(1024) void k_scan(const int* __restrict__ cnt, int n, int* __restrict__ rp){
  __shared__ int sd[1024];
  __shared__ int carry;
  const int t = threadIdx.x;
  if (t == 0) carry = 0;
  __syncthreads();
  int nch = (n + 1023) >> 10;
  for (int c = 0; c < nch; ++c){
    int i = (c << 10) + t;
    int v = (i < n) ? cnt[i] : 0;
    sd[t] = v;
    __syncthreads();
    for (int o = 1; o < 1024; o <<= 1){
      int x = (t >= o) ? sd[t - o] : 0;
      __syncthreads();
      sd[t] += x;
      __syncthreads();
    }
    if (i < n) rp[i] = carry + sd[t] - v;
    __syncthreads();
    if (t == 1023) carry += sd[1023];
    __syncthreads();
  }
  if (t == 0) rp[n] = carry;
}

__global__ void k_scatter(const int* __restrict__ rows, const int* __restrict__ cols,
                          const float* __restrict__ vals, int n, int* __restrict__ cursor,
                          int* __restrict__ cs, float* __restrict__ vs){
  int i = blockIdx.x * blockDim.x + threadIdx.x;
  if (i < n){
    int r = rows[i];
    int p = atomicAdd(&cursor[r], 1);
    cs[p] = cols[i];
    vs[p] = vals[i];
  }
}

// ---------------- fp32 -> bf16 pad-convert: dst[drows][dstride], zero outside src ----------------
__global__ void k_f2b_pad(const float* __restrict__ src, ushort* __restrict__ dst,
                          int srows, int scols, int dstride){
  int r = blockIdx.y;
  int c = blockIdx.x * blockDim.x + threadIdx.x;
  if (c >= dstride) return;
  ushort v = 0;
  if (r < srows && c < scols) v = f2b(src[(size_t)r * scols + c]);
  dst[(size_t)r * dstride + c] = v;
}

// ---------------- SpMM over bf16 table: one wave per row, unroll-2 ----------------
__global__ __launch_bounds__(256) void k_spmm_b(const int* __restrict__ rp, const int* __restrict__ cs,
        const float* __restrict__ vs, const uint* __restrict__ Hb, uint* __restrict__ Ob, int nrows){
  int wid = (blockIdx.x * blockDim.x + threadIdx.x) >> 6;
  int lane = threadIdx.x & 63;
  if (wid >= nrows) return;
  int s = rp[wid], e = rp[wid + 1];
  const bool half = lane < 32;
  float a0=0,a1=0,a2=0,a3=0,a4=0,a5=0;
  float c0_=0,c1_=0,c2_=0,c3_=0,c4_=0,c5_=0;
  int k = s;
  for (; k + 2 <= e; k += 2){
    int i0 = cs[k], i1 = cs[k+1];
    float v0 = vs[k], v1 = vs[k+1];
    const uint* p0 = Hb + (size_t)i0 * PD_U;
    const uint* p1 = Hb + (size_t)i1 * PD_U;
    uint u0 = p0[lane], u1 = p0[lane + 64];
    uint w0 = p1[lane], w1 = p1[lane + 64];
    uint u2 = 0, w2 = 0;
    if (half){ u2 = p0[lane + 128]; w2 = p1[lane + 128]; }
    a0 = fmaf(v0, b2f_lo(u0), a0); a1 = fmaf(v0, b2f_hi(u0), a1);
    a2 = fmaf(v0, b2f_lo(u1), a2); a3 = fmaf(v0, b2f_hi(u1), a3);
    a4 = fmaf(v0, b2f_lo(u2), a4); a5 = fmaf(v0, b2f_hi(u2), a5);
    c0_ = fmaf(v1, b2f_lo(w0), c0_); c1_ = fmaf(v1, b2f_hi(w0), c1_);
    c2_ = fmaf(v1, b2f_lo(w1), c2_); c3_ = fmaf(v1, b2f_hi(w1), c3_);
    c4_ = fmaf(v1, b2f_lo(w2), c4_); c5_ = fmaf(v1, b2f_hi(w2), c5_);
  }
  if (k < e){
    int i0 = cs[k];
    float v0 = vs[k];
    const uint* p0 = Hb + (size_t)i0 * PD_U;
    uint u0 = p0[lane], u1 = p0[lane + 64];
    uint u2 = half ? p0[lane + 128] : 0;
    a0 = fmaf(v0, b2f_lo(u0), a0); a1 = fmaf(v0, b2f_hi(u0), a1);
    a2 = fmaf(v0, b2f_lo(u1), a2); a3 = fmaf(v0, b2f_hi(u1), a3);
    a4 = fmaf(v0, b2f_lo(u2), a4); a5 = fmaf(v0, b2f_hi(u2), a5);
  }
  a0+=c0_; a1+=c1_; a2+=c2_; a3+=c3_; a4+=c4_; a5+=c5_;
  uint* o = Ob + (size_t)wid * PD_U;
  o[lane] = packb(a0, a1);
  o[lane + 64] = packb(a2, a3);
  if (half) o[lane + 128] = packb(a4, a5);
}

// ---------------- MFMA GEMM: C[M,Nvalid] = act(A[M,320]bf16 @ B[n][k]bf16^T) ----------------
// BM=128, BN=160, BK=64, 4 waves (2x2), wave tile 64x80 (4x5 16x16 frags).
__global__ __launch_bounds__(256) void k_mgemm(const ushort* __restrict__ A, const ushort* __restrict__ B,
        const float* __restrict__ bias, const float* __restrict__ bng, const float* __restrict__ bnb,
        ushort* __restrict__ C, int M, int Nvalid, int ldc, int relu){
  __shared__ ushort As[128][72];
  __shared__ ushort Bs[160][72];
  const int t = threadIdx.x;
  const int wid = t >> 6, lane = t & 63;
  const int bm = blockIdx.y << 7;
  const int bn = blockIdx.x * 160;
  const int wm = (wid >> 1) << 6;   // 0 / 64
  const int wn = (wid & 1) * 80;    // 0 / 80
  const int r16 = lane & 15;
  const int h8 = (lane >> 4) << 3;  // k-offset within 32
  f32x4 acc[4][5] = {};
  for (int k0 = 0; k0 < PD; k0 += 64){
    #pragma unroll
    for (int i = 0; i < 4; ++i){
      int q = t + (i << 8);
      int r = q >> 3, c = (q & 7) << 3;
      int gm = bm + r; if (gm >= M) gm = M - 1;
      *(bf16x8*)(&As[r][c]) = *(const bf16x8*)(A + (size_t)gm * PD + k0 + c);
    }
    #pragma unroll
    for (int i = 0; i < 5; ++i){
      int q = t + (i << 8);
      int r = q >> 3, c = (q & 7) << 3;
      *(bf16x8*)(&Bs[r][c]) = *(const bf16x8*)(B + (size_t)(bn + r) * PD + k0 + c);
    }
    __syncthreads();
    #pragma unroll
    for (int kk = 0; kk < 2; ++kk){
      bf16x8 af[4], bfr[5];
      #pragma unroll
      for (int m = 0; m < 4; ++m)
        af[m] = *(const bf16x8*)(&As[wm + m * 16 + r16][kk * 32 + h8]);
      #pragma unroll
      for (int n = 0; n < 5; ++n)
        bfr[n] = *(const bf16x8*)(&Bs[wn + n * 16 + r16][kk * 32 + h8]);
      #pragma unroll
      for (int m = 0; m < 4; ++m)
        #pragma unroll
        for (int n = 0; n < 5; ++n)
          acc[m][n] = __builtin_amdgcn_mfma_f32_16x16x32_bf16(af[m], bfr[n], acc[m][n], 0, 0, 0);
    }
    __syncthreads();
  }
  const int cr = (lane >> 4) << 2;
  #pragma unroll
  for (int m = 0; m < 4; ++m){
    #pragma unroll
    for (int n = 0; n < 5; ++n){
      int col = bn + wn + n * 16 + r16;
      #pragma unroll
      for (int j = 0; j < 4; ++j){
        int row = bm + wm + m * 16 + cr + j;
        if (row >= M) continue;
        float v = acc[m][n][j];
        if (col < Nvalid){
          if (bias) v += bias[col];
          if (bng)  v = v * (bng[col] * BN_SCALE) + bnb[col];
          if (relu) v = fmaxf(v, 0.f);
        } else v = 0.f;
        C[(size_t)row * ldc + col] = f2b(v);
      }
    }
  }
}

// ---------------- residual + LayerNorm; S = LN(0.3*emb + 0.7*H) + emb (bf16 out, padded) ----------------
__global__ __launch_bounds__(64) void k_res_ln(const float* __restrict__ emb, const uint* __restrict__ Hb,
        const float* __restrict__ g, const float* __restrict__ bb, uint* __restrict__ S){
  int row = blockIdx.x, lane = threadIdx.x;
  const float* e = emb + (size_t)row * DIM;
  const uint* h = Hb + (size_t)row * PD_U;
  float x[6], ev[6];
  float sum = 0.f, sq = 0.f;
  #pragma unroll
  for (int j = 0; j < 3; ++j){
    int i = lane + j * 64;
    float e0 = 0.f, e1 = 0.f, h0 = 0.f, h1 = 0.f;
    if (i < 150){
      uint u = h[i];
      h0 = b2f_lo(u); h1 = b2f_hi(u);
      e0 = e[2 * i]; e1 = e[2 * i + 1];
    }
    float v0 = 0.3f * e0 + 0.7f * h0;
    float v1 = 0.3f * e1 + 0.7f * h1;
    if (i >= 150){ v0 = 0.f; v1 = 0.f; }
    x[2*j] = v0; x[2*j+1] = v1; ev[2*j] = e0; ev[2*j+1] = e1;
    sum += v0 + v1; sq += v0 * v0 + v1 * v1;
  }
  #pragma unroll
  for (int o = 32; o > 0; o >>= 1){ sum += __shfl_down(sum, o); sq += __shfl_down(sq, o); }
  sum = __shfl(sum, 0); sq = __shfl(sq, 0);
  const float inv = 1.f / (float)DIM;
  float mu = sum * inv;
  float var = sq * inv - mu * mu;
  float rs = rsqrtf(var + 1e-5f);
  uint* o = S + (size_t)row * PD_U;
  #pragma unroll
  for (int j = 0; j < 3; ++j){
    int i = lane + j * 64;
    if (i >= PD_U) continue;
    uint w = 0;
    if (i < 150){
      float r0 = (x[2*j]   - mu) * rs * g[2*i]   + bb[2*i]   + ev[2*j];
      float r1 = (x[2*j+1] - mu) * rs * g[2*i+1] + bb[2*i+1] + ev[2*j+1];
      w = packb(r0, r1);
    }
    o[i] = w;
  }
}

// ---------------- classifier: [ND,150]bf16 @ [2,150]^T + b -> fp32 out ----------------
__global__ void k_clf(const uint* __restrict__ h2, const float* __restrict__ w,
                      const float* __restrict__ bias, float* __restrict__ out){
  int m = blockIdx.x * blockDim.x + threadIdx.x;
  if (m >= ND) return;
  const uint* hr = h2 + (size_t)m * 80;
  float s0 = bias[0], s1 = bias[1];
  #pragma unroll 5
  for (int i = 0; i < 75; ++i){
    uint u = hr[i];
    float h0 = b2f_lo(u), h1 = b2f_hi(u);
    int k = 2 * i;
    s0 = fmaf(h0, w[k], fmaf(h1, w[k + 1], s0));
    s1 = fmaf(h0, w[DIM2 + k], fmaf(h1, w[DIM2 + k + 1], s1));
  }
  out[m * 2] = s0;
  out[m * 2 + 1] = s1;
}

extern "C" void kernel_launch(void* const* d_in, const int* in_sizes, int n_in,
                              void* d_out, int out_size, void* d_ws, size_t ws_size,
                              hipStream_t stream){
  const int*   a_rows = (const int*)  d_in[0];
  const int*   a_cols = (const int*)  d_in[1];
  const float* a_vals = (const float*)d_in[2];
  const int*   x_rows = (const int*)  d_in[3];
  const int*   x_cols = (const int*)  d_in[4];
  const float* x_vals = (const float*)d_in[5];
  const float* emb    = (const float*)d_in[6];
  const float* w1     = (const float*)d_in[7];
  const float* w2     = (const float*)d_in[8];
  const float* w3     = (const float*)d_in[9];
  const float* ln_g   = (const float*)d_in[10];
  const float* ln_b   = (const float*)d_in[11];
  const float* m_w1   = (const float*)d_in[12];
  const float* m_b1   = (const float*)d_in[13];
  const float* bn1_g  = (const float*)d_in[14];
  const float* bn1_b  = (const float*)d_in[15];
  const float* m_w2   = (const float*)d_in[16];
  const float* m_b2   = (const float*)d_in[17];
  const float* bn2_g  = (const float*)d_in[18];
  const float* bn2_b  = (const float*)d_in[19];
  const float* clf_w  = (const float*)d_in[20];
  const float* clf_b  = (const float*)d_in[21];
  float* out = (float*)d_out;

  char* ws = (char*)d_ws;
  size_t off = 0;
  auto take = [&](size_t nbytes)->void*{
    void* p = ws + off;
    off += (nbytes + 255) & ~(size_t)255;
    return p;
  };
  int*    a_rp   = (int*)   take((NW + 1) * 4);
  int*    a_cs   = (int*)   take((size_t)NNZA * 4);
  float*  a_vs   = (float*) take((size_t)NNZA * 4);
  int*    x_rp   = (int*)   take((ND + 1) * 4);
  int*    x_cs   = (int*)   take((size_t)NNZX * 4);
  float*  x_vs   = (float*) take((size_t)NNZX * 4);
  int*    cursor = (int*)   take((size_t)NW * 4);
  ushort* embb   = (ushort*)take((size_t)NW * PD * 2);
  ushort* Tb     = (ushort*)take((size_t)NW * PD * 2);
  ushort* Hb     = (ushort*)take((size_t)NW * PD * 2);
  ushort* w1b    = (ushort*)take((size_t)PD * PD * 2);
  ushort* w2b    = (ushort*)take((size_t)PD * PD * 2);
  ushort* w3b    = (ushort*)take((size_t)PD * PD * 2);
  ushort* mw1b   = (ushort*)take((size_t)PD * PD * 2);
  ushort* mw2b   = (ushort*)take((size_t)PD * PD * 2);
  // doc-stage buffers alias Hb (H3 is dead once res_ln has produced S in Tb)
  ushort* docHb = Hb;
  ushort* h1b   = Hb + (size_t)ND * PD;
  ushort* h2b   = Hb + (size_t)2 * ND * PD;  // stride 160

  // ---- CSR builds ----
  hipMemsetAsync(cursor, 0, NW * 4, stream);
  k_hist<<<cdiv(NNZA, 256), 256, 0, stream>>>(a_rows, NNZA, cursor);
  k_scan<<<1, 1024, 0, stream>>>(cursor, NW, a_rp);
  k_copy_int<<<cdiv(NW, 256), 256, 0, stream>>>(a_rp, cursor, NW);
  k_scatter<<<cdiv(NNZA, 256), 256, 0, stream>>>(a_rows, a_cols, a_vals, NNZA, cursor, a_cs, a_vs);
  hipMemsetAsync(cursor, 0, ND * 4, stream);
  k_hist<<<cdiv(NNZX, 256), 256, 0, stream>>>(x_rows, NNZX, cursor);
  k_scan<<<1, 1024, 0, stream>>>(cursor, ND, x_rp);
  k_copy_int<<<cdiv(ND, 256), 256, 0, stream>>>(x_rp, cursor, ND);
  k_scatter<<<cdiv(NNZX, 256), 256, 0, stream>>>(x_rows, x_cols, x_vals, NNZX, cursor, x_cs, x_vs);

  // ---- fp32 -> bf16 padded conversions ----
  dim3 cb(cdiv(PD, 256), NW);
  k_f2b_pad<<<cb, 256, 0, stream>>>(emb, embb, NW, DIM, PD);
  dim3 cw(cdiv(PD, 256), PD);
  k_f2b_pad<<<cw, 256, 0, stream>>>(w1, w1b, DIM, DIM, PD);
  k_f2b_pad<<<cw, 256, 0, stream>>>(w2, w2b, DIM, DIM, PD);
  k_f2b_pad<<<cw, 256, 0, stream>>>(w3, w3b, DIM, DIM, PD);
  k_f2b_pad<<<cw, 256, 0, stream>>>(m_w1, mw1b, DIM, DIM, PD);
  k_f2b_pad<<<cw, 256, 0, stream>>>(m_w2, mw2b, DIM2, DIM, PD);

  // ---- word GCN ----
  dim3 gg(2, cdiv(NW, 128));
  k_spmm_b<<<cdiv(NW, 4), 256, 0, stream>>>(a_rp, a_cs, a_vs, (const uint*)embb, (uint*)Tb, NW);
  k_mgemm<<<gg, 256, 0, stream>>>(Tb, w1b, nullptr, nullptr, nullptr, Hb, NW, DIM, PD, 1);
  k_spmm_b<<<cdiv(NW, 4), 256, 0, stream>>>(a_rp, a_cs, a_vs, (const uint*)Hb, (uint*)Tb, NW);
  k_mgemm<<<gg, 256, 0, stream>>>(Tb, w2b, nullptr, nullptr, nullptr, Hb, NW, DIM, PD, 1);
  k_spmm_b<<<cdiv(NW, 4), 256, 0, stream>>>(a_rp, a_cs, a_vs, (const uint*)Hb, (uint*)Tb, NW);
  k_mgemm<<<gg, 256, 0, stream>>>(Tb, w3b, nullptr, nullptr, nullptr, Hb, NW, DIM, PD, 1);
  // ---- residual + LN (S = LN + emb fused into Tb) ----
  k_res_ln<<<NW, 64, 0, stream>>>(emb, (const uint*)Hb, ln_g, ln_b, (uint*)Tb);
  // ---- doc aggregation (single SpMM over summed matrix) ----
  k_spmm_b<<<cdiv(ND, 4), 256, 0, stream>>>(x_rp, x_cs, x_vs, (const uint*)Tb, (uint*)docHb, ND);
  // ---- MLP head ----
  dim3 g1(2, cdiv(ND, 128));
  k_mgemm<<<g1, 256, 0, stream>>>(docHb, mw1b, m_b1, bn1_g, bn1_b, h1b, ND, DIM, PD, 1);
  dim3 g2(1, cdiv(ND, 128));
  k_mgemm<<<g2, 256, 0, stream>>>(h1b, mw2b, m_b2, bn2_g, bn2_b, h2b, ND, DIM2, 160, 1);
  k_clf<<<cdiv(ND, 256), 256, 0, stream>>>((const uint*)h2b, clf_w, clf_b, out);
}

// Round 4
// 557.860 us; speedup vs baseline: 1.9449x; 1.0791x over previous
//
#include <hip/hip_runtime.h>

#define NW 30000
#define ND 8192
#define DIM 300
#define DIM2 150
#define NNZA 600000
#define NNZX 524288
#define PD 320            // padded feature stride (bf16 elems)
#define PD_U 160          // padded stride in uint (2 bf16 each)
#define BN_SCALE 0.99999500003749971f

typedef unsigned int uint;
typedef unsigned short ushort;
typedef __attribute__((ext_vector_type(8))) short bf16x8;
typedef __attribute__((ext_vector_type(4))) float f32x4;
typedef __attribute__((ext_vector_type(4))) uint uint4v;

static inline int cdiv(int a, int b){ return (a + b - 1) / b; }

__device__ __forceinline__ float b2f_lo(uint u){ return __builtin_bit_cast(float, u << 16); }
__device__ __forceinline__ float b2f_hi(uint u){ return __builtin_bit_cast(float, u & 0xffff0000u); }
__device__ __forceinline__ ushort f2b(float f){
  uint u = __builtin_bit_cast(uint, f);
  u += 0x7fffu + ((u >> 16) & 1u);
  return (ushort)(u >> 16);
}
__device__ __forceinline__ uint packb(float x, float y){
  return (uint)f2b(x) | ((uint)f2b(y) << 16);
}

// ---------------- CSR build ----------------
__global__ void k_hist(const int* __restrict__ rows, int n, int* __restrict__ cnt){
  int i = blockIdx.x * blockDim.x + threadIdx.x;
  if (i < n) atomicAdd(&cnt[rows[i]], 1);
}

__global__ void k_copy_int(const int* __restrict__ a, int* __restrict__ b, int n){
  int i = blockIdx.x * blockDim.x + threadIdx.x;
  if (i < n) b[i] = a[i];
}

// hierarchical scan: (1) per-1024-block sums
__global__ __launch_bounds__(1024) void k_bsum(const int* __restrict__ cnt, int n, int* __restrict__ bs){
  __shared__ int sd[1024];
  int t = threadIdx.x;
  int i = blockIdx.x * 1024 + t;
  sd[t] = (i < n) ? cnt[i] : 0;
  __syncthreads();
  #pragma unroll
  for (int o = 512; o > 0; o >>= 1){
    if (t < o) sd[t] += sd[t + o];
    __syncthreads();
  }
  if (t == 0) bs[blockIdx.x] = sd[0];
}

// (2) single-wave exclusive scan of block sums (nb <= 64), writes total to rp[n]
__global__ __launch_bounds__(64) void k_scan_small(int* __restrict__ bs, int nb,
                                                   int* __restrict__ rp, int n){
  int t = threadIdx.x;
  int orig = (t < nb) ? bs[t] : 0;
  int v = orig;
  #pragma unroll
  for (int o = 1; o < 64; o <<= 1){
    int x = __shfl_up(v, o);
    if (t >= o) v += x;
  }
  if (t < nb) bs[t] = v - orig;
  if (t == nb - 1) rp[n] = v;
}

// (3) per-block scan + offset
__global__ __launch_bounds__(1024) void k_scan_apply(const int* __restrict__ cnt, int n,
        const int* __restrict__ bs, int* __restrict__ rp){
  __shared__ int sd[1024];
  int t = threadIdx.x;
  int i = blockIdx.x * 1024 + t;
  int v = (i < n) ? cnt[i] : 0;
  sd[t] = v;
  __syncthreads();
  for (int o = 1; o < 1024; o <<= 1){
    int x = (t >= o) ? sd[t - o] : 0;
    __syncthreads();
    sd[t] += x;
    __syncthreads();
  }
  if (i < n) rp[i] = bs[blockIdx.x] + sd[t] - v;
}

__global__ void k_scatter(const int* __restrict__ rows, const int* __restrict__ cols,
                          const float* __restrict__ vals, int n, int* __restrict__ cursor,
                          int* __restrict__ cs, float* __restrict__ vs){
  int i = blockIdx.x * blockDim.x + threadIdx.x;
  if (i < n){
    int r = rows[i];
    int p = atomicAdd(&cursor[r], 1);
    cs[p] = cols[i];
    vs[p] = vals[i];
  }
}

// ---------------- fp32 -> bf16 pad-convert, 8 cols/thread, uint4 stores ----------------
__global__ void k_f2b_pad8(const float* __restrict__ src, ushort* __restrict__ dst,
                           int srows, int scols, int drows, int dstride){
  int q = blockIdx.x * blockDim.x + threadIdx.x;   // one q = 8 output cols
  int perRow = dstride >> 3;
  int r = q / perRow;
  int c = (q - r * perRow) << 3;
  if (r >= drows) return;
  float x[8];
  #pragma unroll
  for (int j = 0; j < 8; ++j)
    x[j] = (r < srows && c + j < scols) ? src[(size_t)r * scols + c + j] : 0.f;
  uint4v o;
  o.x = packb(x[0], x[1]); o.y = packb(x[2], x[3]);
  o.z = packb(x[4], x[5]); o.w = packb(x[6], x[7]);
  *(uint4v*)(dst + (size_t)r * dstride + c) = o;
}

// ---------------- SpMM over bf16 table: one wave per row, unroll-4 ----------------
__global__ __launch_bounds__(256) void k_spmm_b(const int* __restrict__ rp, const int* __restrict__ cs,
        const float* __restrict__ vs, const uint* __restrict__ Hb, uint* __restrict__ Ob, int nrows){
  int wid = (blockIdx.x * blockDim.x + threadIdx.x) >> 6;
  int lane = threadIdx.x & 63;
  if (wid >= nrows) return;
  int s = rp[wid], e = rp[wid + 1];
  const bool half = lane < 32;
  float acc[4][6] = {};
  int k = s;
  for (; k + 4 <= e; k += 4){
    #pragma unroll
    for (int j = 0; j < 4; ++j){
      int c = cs[k + j];
      float v = vs[k + j];
      const uint* p = Hb + (size_t)c * PD_U;
      uint u0 = p[lane], u1 = p[lane + 64];
      uint u2 = half ? p[lane + 128] : 0;
      acc[j][0] = fmaf(v, b2f_lo(u0), acc[j][0]);
      acc[j][1] = fmaf(v, b2f_hi(u0), acc[j][1]);
      acc[j][2] = fmaf(v, b2f_lo(u1), acc[j][2]);
      acc[j][3] = fmaf(v, b2f_hi(u1), acc[j][3]);
      acc[j][4] = fmaf(v, b2f_lo(u2), acc[j][4]);
      acc[j][5] = fmaf(v, b2f_hi(u2), acc[j][5]);
    }
  }
  for (; k < e; ++k){
    int c = cs[k];
    float v = vs[k];
    const uint* p = Hb + (size_t)c * PD_U;
    uint u0 = p[lane], u1 = p[lane + 64];
    uint u2 = half ? p[lane + 128] : 0;
    acc[0][0] = fmaf(v, b2f_lo(u0), acc[0][0]);
    acc[0][1] = fmaf(v, b2f_hi(u0), acc[0][1]);
    acc[0][2] = fmaf(v, b2f_lo(u1), acc[0][2]);
    acc[0][3] = fmaf(v, b2f_hi(u1), acc[0][3]);
    acc[0][4] = fmaf(v, b2f_lo(u2), acc[0][4]);
    acc[0][5] = fmaf(v, b2f_hi(u2), acc[0][5]);
  }
  #pragma unroll
  for (int d = 0; d < 6; ++d)
    acc[0][d] += (acc[1][d] + acc[2][d]) + acc[3][d];
  uint* o = Ob + (size_t)wid * PD_U;
  o[lane] = packb(acc[0][0], acc[0][1]);
  o[lane + 64] = packb(acc[0][2], acc[0][3]);
  if (half) o[lane + 128] = packb(acc[0][4], acc[0][5]);
}

// ---------------- MFMA GEMM: C[M,Nvalid] = act(A[M,320]bf16 @ B[n][k]bf16^T) ----------------
// BM=128, BN=160, BK=64, 4 waves (2x2), wave tile 64x80 (4x5 16x16 frags).
__global__ __launch_bounds__(256) void k_mgemm(const ushort* __restrict__ A, const ushort* __restrict__ B,
        const float* __restrict__ bias, const float* __restrict__ bng, const float* __restrict__ bnb,
        ushort* __restrict__ C, int M, int Nvalid, int ldc, int relu){
  __shared__ ushort As[128][72];
  __shared__ ushort Bs[160][72];
  const int t = threadIdx.x;
  const int wid = t >> 6, lane = t & 63;
  const int bm = blockIdx.y << 7;
  const int bn = blockIdx.x * 160;
  const int wm = (wid >> 1) << 6;   // 0 / 64
  const int wn = (wid & 1) * 80;    // 0 / 80
  const int r16 = lane & 15;
  const int h8 = (lane >> 4) << 3;  // k-offset within 32
  f32x4 acc[4][5] = {};
  for (int k0 = 0; k0 < PD; k0 += 64){
    #pragma unroll
    for (int i = 0; i < 4; ++i){
      int q = t + (i << 8);
      int r = q >> 3, c = (q & 7) << 3;
      int gm = bm + r; if (gm >= M) gm = M - 1;
      *(bf16x8*)(&As[r][c]) = *(const bf16x8*)(A + (size_t)gm * PD + k0 + c);
    }
    #pragma unroll
    for (int i = 0; i < 5; ++i){
      int q = t + (i << 8);
      int r = q >> 3, c = (q & 7) << 3;
      *(bf16x8*)(&Bs[r][c]) = *(const bf16x8*)(B + (size_t)(bn + r) * PD + k0 + c);
    }
    __syncthreads();
    #pragma unroll
    for (int kk = 0; kk < 2; ++kk){
      bf16x8 af[4], bfr[5];
      #pragma unroll
      for (int m = 0; m < 4; ++m)
        af[m] = *(const bf16x8*)(&As[wm + m * 16 + r16][kk * 32 + h8]);
      #pragma unroll
      for (int n = 0; n < 5; ++n)
        bfr[n] = *(const bf16x8*)(&Bs[wn + n * 16 + r16][kk * 32 + h8]);
      #pragma unroll
      for (int m = 0; m < 4; ++m)
        #pragma unroll
        for (int n = 0; n < 5; ++n)
          acc[m][n] = __builtin_amdgcn_mfma_f32_16x16x32_bf16(af[m], bfr[n], acc[m][n], 0, 0, 0);
    }
    __syncthreads();
  }
  const int cr = (lane >> 4) << 2;
  #pragma unroll
  for (int m = 0; m < 4; ++m){
    #pragma unroll
    for (int n = 0; n < 5; ++n){
      int col = bn + wn + n * 16 + r16;
      #pragma unroll
      for (int j = 0; j < 4; ++j){
        int row = bm + wm + m * 16 + cr + j;
        if (row >= M) continue;
        float v = acc[m][n][j];
        if (col < Nvalid){
          if (bias) v += bias[col];
          if (bng)  v = v * (bng[col] * BN_SCALE) + bnb[col];
          if (relu) v = fmaxf(v, 0.f);
        } else v = 0.f;
        C[(size_t)row * ldc + col] = f2b(v);
      }
    }
  }
}

// ---------------- residual + LayerNorm; S = LN(0.3*emb + 0.7*H) + emb (bf16 out, padded) ----------------
__global__ __launch_bounds__(64) void k_res_ln(const float* __restrict__ emb, const uint* __restrict__ Hb,
        const float* __restrict__ g, const float* __restrict__ bb, uint* __restrict__ S){
  int row = blockIdx.x, lane = threadIdx.x;
  const float* e = emb + (size_t)row * DIM;
  const uint* h = Hb + (size_t)row * PD_U;
  float x[6], ev[6];
  float sum = 0.f, sq = 0.f;
  #pragma unroll
  for (int j = 0; j < 3; ++j){
    int i = lane + j * 64;
    float e0 = 0.f, e1 = 0.f, h0 = 0.f, h1 = 0.f;
    if (i < 150){
      uint u = h[i];
      h0 = b2f_lo(u); h1 = b2f_hi(u);
      e0 = e[2 * i]; e1 = e[2 * i + 1];
    }
    float v0 = 0.3f * e0 + 0.7f * h0;
    float v1 = 0.3f * e1 + 0.7f * h1;
    if (i >= 150){ v0 = 0.f; v1 = 0.f; }
    x[2*j] = v0; x[2*j+1] = v1; ev[2*j] = e0; ev[2*j+1] = e1;
    sum += v0 + v1; sq += v0 * v0 + v1 * v1;
  }
  #pragma unroll
  for (int o = 32; o > 0; o >>= 1){ sum += __shfl_down(sum, o); sq += __shfl_down(sq, o); }
  sum = __shfl(sum, 0); sq = __shfl(sq, 0);
  const float inv = 1.f / (float)DIM;
  float mu = sum * inv;
  float var = sq * inv - mu * mu;
  float rs = rsqrtf(var + 1e-5f);
  uint* o = S + (size_t)row * PD_U;
  #pragma unroll
  for (int j = 0; j < 3; ++j){
    int i = lane + j * 64;
    if (i >= PD_U) continue;
    uint w = 0;
    if (i < 150){
      float r0 = (x[2*j]   - mu) * rs * g[2*i]   + bb[2*i]   + ev[2*j];
      float r1 = (x[2*j+1] - mu) * rs * g[2*i+1] + bb[2*i+1] + ev[2*j+1];
      w = packb(r0, r1);
    }
    o[i] = w;
  }
}

// ---------------- classifier: [ND,150]bf16 @ [2,150]^T + b -> fp32 out ----------------
__global__ void k_clf(const uint* __restrict__ h2, const float* __restrict__ w,
                      const float* __restrict__ bias, float* __restrict__ out){
  int m = blockIdx.x * blockDim.x + threadIdx.x;
  if (m >= ND) return;
  const uint* hr = h2 + (size_t)m * 80;
  float s0 = bias[0], s1 = bias[1];
  #pragma unroll 5
  for (int i = 0; i < 75; ++i){
    uint u = hr[i];
    float h0 = b2f_lo(u), h1 = b2f_hi(u);
    int k = 2 * i;
    s0 = fmaf(h0, w[k], fmaf(h1, w[k + 1], s0));
    s1 = fmaf(h0, w[DIM2 + k], fmaf(h1, w[DIM2 + k + 1], s1));
  }
  out[m * 2] = s0;
  out[m * 2 + 1] = s1;
}

extern "C" void kernel_launch(void* const* d_in, const int* in_sizes, int n_in,
                              void* d_out, int out_size, void* d_ws, size_t ws_size,
                              hipStream_t stream){
  const int*   a_rows = (const int*)  d_in[0];
  const int*   a_cols = (const int*)  d_in[1];
  const float* a_vals = (const float*)d_in[2];
  const int*   x_rows = (const int*)  d_in[3];
  const int*   x_cols = (const int*)  d_in[4];
  const float* x_vals = (const float*)d_in[5];
  const float* emb    = (const float*)d_in[6];
  const float* w1     = (const float*)d_in[7];
  const float* w2     = (const float*)d_in[8];
  const float* w3     = (const float*)d_in[9];
  const float* ln_g   = (const float*)d_in[10];
  const float* ln_b   = (const float*)d_in[11];
  const float* m_w1   = (const float*)d_in[12];
  const float* m_b1   = (const float*)d_in[13];
  const float* bn1_g  = (const float*)d_in[14];
  const float* bn1_b  = (const float*)d_in[15];
  const float* m_w2   = (const float*)d_in[16];
  const float* m_b2   = (const float*)d_in[17];
  const float* bn2_g  = (const float*)d_in[18];
  const float* bn2_b  = (const float*)d_in[19];
  const float* clf_w  = (const float*)d_in[20];
  const float* clf_b  = (const float*)d_in[21];
  float* out = (float*)d_out;

  char* ws = (char*)d_ws;
  size_t off = 0;
  auto take = [&](size_t nbytes)->void*{
    void* p = ws + off;
    off += (nbytes + 255) & ~(size_t)255;
    return p;
  };
  int*    a_rp   = (int*)   take((NW + 1) * 4);
  int*    a_cs   = (int*)   take((size_t)NNZA * 4);
  float*  a_vs   = (float*) take((size_t)NNZA * 4);
  int*    x_rp   = (int*)   take((ND + 1) * 4);
  int*    x_cs   = (int*)   take((size_t)NNZX * 4);
  float*  x_vs   = (float*) take((size_t)NNZX * 4);
  int*    cursor = (int*)   take((size_t)NW * 4);
  int*    bsums  = (int*)   take(64 * 4);
  ushort* embb   = (ushort*)take((size_t)NW * PD * 2);
  ushort* Tb     = (ushort*)take((size_t)NW * PD * 2);
  ushort* Hb     = (ushort*)take((size_t)NW * PD * 2);
  ushort* w1b    = (ushort*)take((size_t)PD * PD * 2);
  ushort* w2b    = (ushort*)take((size_t)PD * PD * 2);
  ushort* w3b    = (ushort*)take((size_t)PD * PD * 2);
  ushort* mw1b   = (ushort*)take((size_t)PD * PD * 2);
  ushort* mw2b   = (ushort*)take((size_t)PD * PD * 2);
  // doc-stage buffers alias Hb (H3 is dead once res_ln has produced S in Tb)
  ushort* docHb = Hb;
  ushort* h1b   = Hb + (size_t)ND * PD;
  ushort* h2b   = Hb + (size_t)2 * ND * PD;  // stride 160

  // ---- CSR build for A ----
  int nbA = cdiv(NW, 1024);
  hipMemsetAsync(cursor, 0, NW * 4, stream);
  k_hist<<<cdiv(NNZA, 256), 256, 0, stream>>>(a_rows, NNZA, cursor);
  k_bsum<<<nbA, 1024, 0, stream>>>(cursor, NW, bsums);
  k_scan_small<<<1, 64, 0, stream>>>(bsums, nbA, a_rp, NW);
  k_scan_apply<<<nbA, 1024, 0, stream>>>(cursor, NW, bsums, a_rp);
  k_copy_int<<<cdiv(NW, 256), 256, 0, stream>>>(a_rp, cursor, NW);
  k_scatter<<<cdiv(NNZA, 256), 256, 0, stream>>>(a_rows, a_cols, a_vals, NNZA, cursor, a_cs, a_vs);
  // ---- CSR build for X ----
  int nbX = cdiv(ND, 1024);
  hipMemsetAsync(cursor, 0, ND * 4, stream);
  k_hist<<<cdiv(NNZX, 256), 256, 0, stream>>>(x_rows, NNZX, cursor);
  k_bsum<<<nbX, 1024, 0, stream>>>(cursor, ND, bsums);
  k_scan_small<<<1, 64, 0, stream>>>(bsums, nbX, x_rp, ND);
  k_scan_apply<<<nbX, 1024, 0, stream>>>(cursor, ND, bsums, x_rp);
  k_copy_int<<<cdiv(ND, 256), 256, 0, stream>>>(x_rp, cursor, ND);
  k_scatter<<<cdiv(NNZX, 256), 256, 0, stream>>>(x_rows, x_cols, x_vals, NNZX, cursor, x_cs, x_vs);

  // ---- fp32 -> bf16 padded conversions (8 cols/thread) ----
  k_f2b_pad8<<<cdiv(NW * 40, 256), 256, 0, stream>>>(emb, embb, NW, DIM, NW, PD);
  k_f2b_pad8<<<cdiv(PD * 40, 256), 256, 0, stream>>>(w1, w1b, DIM, DIM, PD, PD);
  k_f2b_pad8<<<cdiv(PD * 40, 256), 256, 0, stream>>>(w2, w2b, DIM, DIM, PD, PD);
  k_f2b_pad8<<<cdiv(PD * 40, 256), 256, 0, stream>>>(w3, w3b, DIM, DIM, PD, PD);
  k_f2b_pad8<<<cdiv(PD * 40, 256), 256, 0, stream>>>(m_w1, mw1b, DIM, DIM, PD, PD);
  k_f2b_pad8<<<cdiv(PD * 40, 256), 256, 0, stream>>>(m_w2, mw2b, DIM2, DIM, PD, PD);

  // ---- word GCN ----
  dim3 gg(2, cdiv(NW, 128));
  k_spmm_b<<<cdiv(NW, 4), 256, 0, stream>>>(a_rp, a_cs, a_vs, (const uint*)embb, (uint*)Tb, NW);
  k_mgemm<<<gg, 256, 0, stream>>>(Tb, w1b, nullptr, nullptr, nullptr, Hb, NW, DIM, PD, 1);
  k_spmm_b<<<cdiv(NW, 4), 256, 0, stream>>>(a_rp, a_cs, a_vs, (const uint*)Hb, (uint*)Tb, NW);
  k_mgemm<<<gg, 256, 0, stream>>>(Tb, w2b, nullptr, nullptr, nullptr, Hb, NW, DIM, PD, 1);
  k_spmm_b<<<cdiv(NW, 4), 256, 0, stream>>>(a_rp, a_cs, a_vs, (const uint*)Hb, (uint*)Tb, NW);
  k_mgemm<<<gg, 256, 0, stream>>>(Tb, w3b, nullptr, nullptr, nullptr, Hb, NW, DIM, PD, 1);
  // ---- residual + LN (S = LN + emb fused into Tb) ----
  k_res_ln<<<NW, 64, 0, stream>>>(emb, (const uint*)Hb, ln_g, ln_b, (uint*)Tb);
  // ---- doc aggregation (single SpMM over summed matrix) ----
  k_spmm_b<<<cdiv(ND, 4), 256, 0, stream>>>(x_rp, x_cs, x_vs, (const uint*)Tb, (uint*)docHb, ND);
  // ---- MLP head ----
  dim3 g1(2, cdiv(ND, 128));
  k_mgemm<<<g1, 256, 0, stream>>>(docHb, mw1b, m_b1, bn1_g, bn1_b, h1b, ND, DIM, PD, 1);
  dim3 g2(1, cdiv(ND, 128));
  k_mgemm<<<g2, 256, 0, stream>>>(h1b, mw2b, m_b2, bn2_g, bn2_b, h2b, ND, DIM2, 160, 1);
  k_clf<<<cdiv(ND, 256), 256, 0, stream>>>((const uint*)h2b, clf_w, clf_b, out);
}